// Round 13
// baseline (618.404 us; speedup 1.0000x reference)
//
#include <hip/hip_runtime.h>
#include <cstdio>
#include <math.h>

static constexpr int B_ = 64, N_ = 200, H_ = 256, NH_ = 8, G_ = 2, L_ = 3, F_ = 512;
static constexpr int BN_ = B_ * N_;  // 12800

typedef unsigned short u16;
typedef __attribute__((ext_vector_type(8))) short short8;
typedef __attribute__((ext_vector_type(4))) float f32x4;

#define LDSP(p) ((__attribute__((address_space(3))) unsigned int*)(p))
#define GLBP(p) ((const __attribute__((address_space(1))) unsigned int*)(p))

__device__ __forceinline__ float wave_sum64(float v) {
#pragma unroll
  for (int off = 32; off; off >>= 1) v += __shfl_xor(v, off);
  return v;
}
__device__ __forceinline__ float sigmoidf_(float x) { return 1.f / (1.f + __expf(-x)); }
__device__ __forceinline__ u16 f2bf(float x) {  // RNE f32->bf16
  unsigned u = __float_as_uint(x);
  return (u16)((u + 0x7FFFu + ((u >> 16) & 1u)) >> 16);
}
__device__ __forceinline__ float bf2f(u16 x) { return __uint_as_float((unsigned)x << 16); }

// ================= bf16 MFMA GEMM =================
// C[M][Nn] = act(A @ Bt^T + bias + res). A: bf16 [M][K]; Bt: bf16 [Nn][K].
template <int ACT, bool HAS_BIAS, bool HAS_RES, bool OUT_BF>
__global__ __launch_bounds__(256) void gemm_bf16(
    const u16* __restrict__ A, const u16* __restrict__ Bt,
    const float* __restrict__ bias, const float* __restrict__ res,
    float* __restrict__ Cf, u16* __restrict__ Cb, int M, int Nn, int K) {
  __shared__ u16 As[128 * 64];
  __shared__ u16 Bs[128 * 64];
  char* asB = (char*)As;
  char* bsB = (char*)Bs;
  const int tid = threadIdx.x;
  const int m0 = blockIdx.x * 128, n0 = blockIdx.y * 128;
  const int lane = tid & 63;
  const int wid = tid >> 6;
  const int wr = (wid >> 1) * 64, wc = (wid & 1) * 64;
  const int Kb = K * 2;
  const char* Ab = (const char*)A + (size_t)m0 * Kb;
  const char* Bb = (const char*)Bt + (size_t)n0 * Kb;
  f32x4 acc[4][4];
#pragma unroll
  for (int i = 0; i < 4; ++i)
#pragma unroll
    for (int j = 0; j < 4; ++j)
#pragma unroll
      for (int r = 0; r < 4; ++r) acc[i][j][r] = 0.f;

  for (int k0 = 0; k0 < K; k0 += 64) {
    if (k0) __syncthreads();
#pragma unroll
    for (int it = 0; it < 4; ++it) {
      const unsigned o = (unsigned)(it * 256 + tid) * 16;
      const int row = o >> 7;
      const unsigned bc = (o & 127u) ^ (unsigned)((row & 7) << 4);
      const unsigned wb = o & ~1023u;
      __builtin_amdgcn_global_load_lds(GLBP(Ab + (size_t)row * Kb + k0 * 2 + bc),
                                       LDSP(asB + wb), 16, 0, 0);
      __builtin_amdgcn_global_load_lds(GLBP(Bb + (size_t)row * Kb + k0 * 2 + bc),
                                       LDSP(bsB + wb), 16, 0, 0);
    }
    __syncthreads();
#pragma unroll
    for (int kk = 0; kk < 2; ++kk) {
      short8 aF[4], bF[4];
#pragma unroll
      for (int i = 0; i < 4; ++i) {
        const int ar = wr + i * 16 + (lane & 15);
        const unsigned ac = (unsigned)(kk * 64 + (lane >> 4) * 16) ^ (unsigned)((ar & 7) << 4);
        aF[i] = *(const short8*)(asB + ar * 128 + ac);
        const int br = wc + i * 16 + (lane & 15);
        const unsigned bc2 = (unsigned)(kk * 64 + (lane >> 4) * 16) ^ (unsigned)((br & 7) << 4);
        bF[i] = *(const short8*)(bsB + br * 128 + bc2);
      }
#pragma unroll
      for (int i = 0; i < 4; ++i)
#pragma unroll
        for (int j = 0; j < 4; ++j)
          acc[i][j] = __builtin_amdgcn_mfma_f32_16x16x32_bf16(aF[i], bF[j], acc[i][j], 0, 0, 0);
    }
  }
#pragma unroll
  for (int i = 0; i < 4; ++i) {
    const int gm0 = m0 + wr + i * 16 + (lane >> 4) * 4;
#pragma unroll
    for (int j = 0; j < 4; ++j) {
      const int gn = n0 + wc + j * 16 + (lane & 15);
      const float bv = HAS_BIAS ? bias[gn] : 0.f;
#pragma unroll
      for (int r = 0; r < 4; ++r) {
        const int gm = gm0 + r;
        float v = acc[i][j][r] + bv;
        if (HAS_RES) v += res[(size_t)gm * Nn + gn];
        if (ACT == 1) v = fmaxf(v, 0.f);
        if (OUT_BF)
          Cb[(size_t)gm * Nn + gn] = f2bf(v);
        else
          Cf[(size_t)gm * Nn + gn] = v;
      }
    }
  }
}

// ================= fused GEMM(+bias+res) + LayerNorm, Nn=256, pipelined =====
template <int K>
__global__ __launch_bounds__(256) void gemm_ln(
    const u16* __restrict__ A, const u16* __restrict__ Bt,
    const float* __restrict__ bias, const float* __restrict__ res,
    const float* __restrict__ sb, float* __restrict__ out, u16* __restrict__ outB) {
  __shared__ u16 As[2][64 * 64];
  __shared__ u16 Bs[2][256 * 64];
  __shared__ float2 red[64][4];
  const int tid = threadIdx.x;
  const int m0 = blockIdx.x * 64;
  const int lane = tid & 63, wid = tid >> 6;
  const int wc = wid * 64;
  const int Kb = K * 2;
  const char* Ab = (const char*)A + (size_t)m0 * Kb;
  const char* Bb = (const char*)Bt;
  constexpr int T = K / 64;
  f32x4 acc[4][4];
#pragma unroll
  for (int i = 0; i < 4; ++i)
#pragma unroll
    for (int j = 0; j < 4; ++j)
#pragma unroll
      for (int r = 0; r < 4; ++r) acc[i][j][r] = 0.f;

  auto stage = [&](int buf, int k0) {  // 10 vm ops per thread
#pragma unroll
    for (int it = 0; it < 2; ++it) {
      const unsigned o = (unsigned)(it * 256 + tid) * 16;
      const int row = o >> 7;
      const unsigned bc = (o & 127u) ^ (unsigned)((row & 7) << 4);
      const unsigned wb = o & ~1023u;
      __builtin_amdgcn_global_load_lds(GLBP(Ab + (size_t)row * Kb + k0 * 2 + bc),
                                       LDSP((char*)As[buf] + wb), 16, 0, 0);
    }
#pragma unroll
    for (int it = 0; it < 8; ++it) {
      const unsigned o = (unsigned)(it * 256 + tid) * 16;
      const int row = o >> 7;
      const unsigned bc = (o & 127u) ^ (unsigned)((row & 7) << 4);
      const unsigned wb = o & ~1023u;
      __builtin_amdgcn_global_load_lds(GLBP(Bb + (size_t)row * Kb + k0 * 2 + bc),
                                       LDSP((char*)Bs[buf] + wb), 16, 0, 0);
    }
  };

  stage(0, 0);
  stage(1, 64);
  asm volatile("s_waitcnt vmcnt(10)" ::: "memory");
  __builtin_amdgcn_s_barrier();

  for (int t = 0; t < T; ++t) {
    const int cur = t & 1;
    const char* asB = (const char*)As[cur];
    const char* bsB = (const char*)Bs[cur];
#pragma unroll
    for (int kk = 0; kk < 2; ++kk) {
      short8 aF[4], bF[4];
#pragma unroll
      for (int i = 0; i < 4; ++i) {
        const int ar = i * 16 + (lane & 15);
        const unsigned ac = (unsigned)(kk * 64 + (lane >> 4) * 16) ^ (unsigned)((ar & 7) << 4);
        aF[i] = *(const short8*)(asB + ar * 128 + ac);
        const int br = wc + i * 16 + (lane & 15);
        const unsigned bc2 = (unsigned)(kk * 64 + (lane >> 4) * 16) ^ (unsigned)((br & 7) << 4);
        bF[i] = *(const short8*)(bsB + br * 128 + bc2);
      }
#pragma unroll
      for (int i = 0; i < 4; ++i)
#pragma unroll
        for (int j = 0; j < 4; ++j)
          acc[i][j] = __builtin_amdgcn_mfma_f32_16x16x32_bf16(aF[i], bF[j], acc[i][j], 0, 0, 0);
    }
    asm volatile("s_waitcnt lgkmcnt(0)" ::: "memory");
    __builtin_amdgcn_s_barrier();
    if (t + 2 < T) {
      stage(cur, (t + 2) * 64);
      asm volatile("s_waitcnt vmcnt(10)" ::: "memory");
      __builtin_amdgcn_s_barrier();
    } else if (t + 1 < T) {
      asm volatile("s_waitcnt vmcnt(0)" ::: "memory");
      __builtin_amdgcn_s_barrier();
    }
  }
#pragma unroll
  for (int i = 0; i < 4; ++i) {
#pragma unroll
    for (int j = 0; j < 4; ++j) {
      const int gn = wc + j * 16 + (lane & 15);
      const float bv = bias[gn];
#pragma unroll
      for (int r = 0; r < 4; ++r) {
        const int gm = m0 + i * 16 + (lane >> 4) * 4 + r;
        acc[i][j][r] += bv + res[(size_t)gm * 256 + gn];
      }
    }
  }
#pragma unroll
  for (int i = 0; i < 4; ++i) {
#pragma unroll
    for (int r = 0; r < 4; ++r) {
      float s = 0.f, q = 0.f;
#pragma unroll
      for (int j = 0; j < 4; ++j) {
        const float v = acc[i][j][r];
        s += v;
        q += v * v;
      }
#pragma unroll
      for (int off = 1; off < 16; off <<= 1) {
        s += __shfl_xor(s, off);
        q += __shfl_xor(q, off);
      }
      if ((lane & 15) == 0) red[i * 16 + (lane >> 4) * 4 + r][wid] = make_float2(s, q);
    }
  }
  __syncthreads();
#pragma unroll
  for (int i = 0; i < 4; ++i) {
#pragma unroll
    for (int r = 0; r < 4; ++r) {
      const int row = i * 16 + (lane >> 4) * 4 + r;
      const float2 p0 = red[row][0], p1 = red[row][1], p2 = red[row][2], p3 = red[row][3];
      const float S = p0.x + p1.x + p2.x + p3.x;
      const float Q = p0.y + p1.y + p2.y + p3.y;
      const float mean = S * (1.f / 256.f);
      const float var = Q * (1.f / 256.f) - mean * mean;
      const float rstd = rsqrtf(var + 1e-5f);
      const int gm = m0 + row;
#pragma unroll
      for (int j = 0; j < 4; ++j) {
        const int gn = wc + j * 16 + (lane & 15);
        const float y = (acc[i][j][r] - mean) * rstd * sb[gn] + sb[256 + gn];
        out[(size_t)gm * 256 + gn] = y;
        outB[(size_t)gm * 256 + gn] = f2bf(y);
      }
    }
  }
}

// ================= GAT projection -> transposed slabs =================
__global__ __launch_bounds__(256) void gat_projT(
    const u16* __restrict__ Wt, const u16* __restrict__ actB, u16* __restrict__ xpT) {
  __shared__ u16 As[128 * 64];
  __shared__ u16 Bs[128 * 64];
  char* asB = (char*)As;
  char* bsB = (char*)Bs;
  const int tid = threadIdx.x;
  const int m0 = blockIdx.x * 128;
  const int n0 = blockIdx.y * 128;
  const int b = blockIdx.z;
  const int lane = tid & 63;
  const int wid = tid >> 6;
  const int wr = (wid >> 1) * 64, wc = (wid & 1) * 64;
  const char* Ab = (const char*)Wt + (size_t)m0 * 512;
  const char* Bb = (const char*)actB + ((size_t)b * 200 + n0) * 512;
  f32x4 acc[4][4];
#pragma unroll
  for (int i = 0; i < 4; ++i)
#pragma unroll
    for (int j = 0; j < 4; ++j)
#pragma unroll
      for (int r = 0; r < 4; ++r) acc[i][j][r] = 0.f;

  for (int k0 = 0; k0 < 256; k0 += 64) {
    if (k0) __syncthreads();
#pragma unroll
    for (int it = 0; it < 4; ++it) {
      const unsigned o = (unsigned)(it * 256 + tid) * 16;
      const int row = o >> 7;
      const unsigned bc = (o & 127u) ^ (unsigned)((row & 7) << 4);
      const unsigned wb = o & ~1023u;
      __builtin_amdgcn_global_load_lds(GLBP(Ab + (size_t)row * 512 + k0 * 2 + bc),
                                       LDSP(asB + wb), 16, 0, 0);
      __builtin_amdgcn_global_load_lds(GLBP(Bb + (size_t)row * 512 + k0 * 2 + bc),
                                       LDSP(bsB + wb), 16, 0, 0);
    }
    __syncthreads();
#pragma unroll
    for (int kk = 0; kk < 2; ++kk) {
      short8 aF[4], bF[4];
#pragma unroll
      for (int i = 0; i < 4; ++i) {
        const int ar = wr + i * 16 + (lane & 15);
        const unsigned ac = (unsigned)(kk * 64 + (lane >> 4) * 16) ^ (unsigned)((ar & 7) << 4);
        aF[i] = *(const short8*)(asB + ar * 128 + ac);
        const int br = wc + i * 16 + (lane & 15);
        const unsigned bc2 = (unsigned)(kk * 64 + (lane >> 4) * 16) ^ (unsigned)((br & 7) << 4);
        bF[i] = *(const short8*)(bsB + br * 128 + bc2);
      }
#pragma unroll
      for (int i = 0; i < 4; ++i)
#pragma unroll
        for (int j = 0; j < 4; ++j)
          acc[i][j] = __builtin_amdgcn_mfma_f32_16x16x32_bf16(aF[i], bF[j], acc[i][j], 0, 0, 0);
    }
  }
  u16* outb = xpT + (size_t)b * 524288;
#pragma unroll
  for (int i = 0; i < 4; ++i) {
    const int gm0 = m0 + wr + i * 16 + (lane >> 4) * 4;
#pragma unroll
    for (int j = 0; j < 4; ++j) {
      const int gn = n0 + wc + j * 16 + (lane & 15);
#pragma unroll
      for (int r = 0; r < 4; ++r) {
        const int gm = gm0 + r;
        outb[(size_t)gm * 256 + gn] = (gn < N_) ? f2bf(acc[i][j][r]) : (u16)0;
      }
    }
  }
}

// ================= GAT message MFMA v6: j=32 x d=128, grid 896 (3/CU) ====
// out[b,j,d] = xin[b,j,d] + relu( (1/8) sum_{h,i} P[b,h,j,i]*xpT[b,h,d,i] + bias[d] )
// LDS 48KB -> 3 blocks/CU. Same-b blocks co-located per XCD.
__global__ __launch_bounds__(256) void gat_msg_mfma(
    const u16* __restrict__ xpT, const float* __restrict__ asrcH,
    const float4* __restrict__ statsH, const unsigned* __restrict__ adjTW,
    const float* __restrict__ bias, const float* __restrict__ xin,
    float* __restrict__ xout, u16* __restrict__ xoutB) {
  __shared__ u16 Bs[2][128 * 64];  // 32 KB
  __shared__ u16 Ps[2][32 * 64];   // 8 KB
  __shared__ float asL[8][256];    // 8 KB
  const int tid = threadIdx.x;
  const int Lx = blockIdx.x;           // 896, XCD-swizzled
  const int xcd = Lx & 7;
  const int slot = Lx >> 3;            // 0..111
  const int r14 = slot % 14;
  const int b = xcd + 8 * (slot / 14);
  const int q = r14 >> 1;              // j-tile 0..6
  const int half = r14 & 1;            // d half
  const int m0 = q * 32;
  const int n0 = half * 128;
  const int lane = tid & 63, wid = tid >> 6;
  const int wc = wid * 32;
  const char* baseB = (const char*)xpT + ((size_t)b << 20) + (size_t)n0 * 512;
  f32x4 acc[2][2];
#pragma unroll
  for (int i = 0; i < 2; ++i)
#pragma unroll
    for (int j = 0; j < 2; ++j)
#pragma unroll
      for (int r = 0; r < 4; ++r) acc[i][j][r] = 0.f;

  // ---- per-thread hoisted state (j fixed across all tiles) ----
  const int jrow = tid >> 3;         // 0..31
  const int ib = (tid & 7) << 3;     // 0..56
  const int gj = m0 + jrow;
  const int jc = gj < N_ ? gj : N_ - 1;
  float4 stR[8];
#pragma unroll
  for (int h = 0; h < 8; ++h) stR[h] = statsH[(((size_t)(b * 8 + h)) << 8) + jc];
  const uint4 aw0 = *(const uint4*)&adjTW[((size_t)b * 256 + jc) * 8];
  const uint4 aw1 = *(const uint4*)&adjTW[((size_t)b * 256 + jc) * 8 + 4];
  const unsigned adjR[8] = {aw0.x, aw0.y, aw0.z, aw0.w, aw1.x, aw1.y, aw1.z, aw1.w};
#pragma unroll
  for (int e = 0; e < 8; ++e) {
    const int idx = e * 256 + tid;
    asL[idx >> 8][idx & 255] = asrcH[((size_t)b * 2048) + idx];
  }

  auto stageB = [&](int buf, int t) {  // 4 vm ops per thread (16 KB tile)
    const size_t off = (size_t)(t >> 2) * 131072 + (size_t)((t & 3) * 128);
    char* bD = (char*)Bs[buf];
#pragma unroll
    for (int it = 0; it < 4; ++it) {
      const unsigned o = (unsigned)(it * 256 + tid) * 16;
      const int row = o >> 7;
      const unsigned bc = (o & 127u) ^ (unsigned)((row & 7) << 4);
      const unsigned wb = o & ~1023u;
      __builtin_amdgcn_global_load_lds(GLBP(baseB + off + (size_t)row * 512 + bc),
                                       LDSP(bD + wb), 16, 0, 0);
    }
  };
  auto computeP = [&](int buf, int t) {  // pure LDS + VALU
    const int h = t >> 2, k0 = (t & 3) * 64;
    const float4 st = stR[h];
    const unsigned wbits = adjR[(k0 + ib) >> 5] >> ((k0 + ib) & 31);
    const float* asp = &asL[h][k0 + ib];
    float pv[8];
#pragma unroll
    for (int u = 0; u < 8; ++u) {
      float x = st.x + asp[u];
      x = fmaxf(x, 0.2f * x);                    // leaky_relu(., 0.2)
      const float pe = __expf(x - st.y) * st.z;  // exp(lrelu - mx) / sum
      pv[u] = ((wbits >> u) & 1u) ? pe : 0.f;
    }
    unsigned pk[4];
#pragma unroll
    for (int qx = 0; qx < 4; ++qx)
      pk[qx] = (unsigned)f2bf(pv[2 * qx]) | ((unsigned)f2bf(pv[2 * qx + 1]) << 16);
    const unsigned ad2 =
        (unsigned)(jrow * 128) + (((unsigned)(ib * 2)) ^ (((unsigned)(jrow & 7)) << 4));
    *(uint4*)((char*)Ps[buf] + ad2) = make_uint4(pk[0], pk[1], pk[2], pk[3]);
  };

  // prologue
  stageB(0, 0);
  stageB(1, 1);
  asm volatile("s_waitcnt lgkmcnt(0)" ::: "memory");  // asL writes done
  __builtin_amdgcn_s_barrier();                       // asL published
  computeP(0, 0);
  asm volatile("s_waitcnt lgkmcnt(0)" ::: "memory");  // P(0) writes done
  asm volatile("s_waitcnt vmcnt(4)" ::: "memory");    // buf0 B done; buf1 outstanding
  __builtin_amdgcn_s_barrier();

  for (int t = 0; t < 32; ++t) {
    const int cur = t & 1;
    if (t + 1 < 32) computeP(cur ^ 1, t + 1);
    const char* pB = (const char*)Ps[cur];
    const char* bB = (const char*)Bs[cur];
#pragma unroll
    for (int kk = 0; kk < 2; ++kk) {
      short8 aF[2], bF[2];
#pragma unroll
      for (int i = 0; i < 2; ++i) {
        const int ar = i * 16 + (lane & 15);
        const unsigned ac = (unsigned)(kk * 64 + (lane >> 4) * 16) ^ (unsigned)((ar & 7) << 4);
        aF[i] = *(const short8*)(pB + ar * 128 + ac);
      }
#pragma unroll
      for (int j = 0; j < 2; ++j) {
        const int br = wc + j * 16 + (lane & 15);
        const unsigned bc2 = (unsigned)(kk * 64 + (lane >> 4) * 16) ^ (unsigned)((br & 7) << 4);
        bF[j] = *(const short8*)(bB + br * 128 + bc2);
      }
#pragma unroll
      for (int i = 0; i < 2; ++i)
#pragma unroll
        for (int j = 0; j < 2; ++j)
          acc[i][j] = __builtin_amdgcn_mfma_f32_16x16x32_bf16(aF[i], bF[j], acc[i][j], 0, 0, 0);
    }
    asm volatile("s_waitcnt lgkmcnt(0)" ::: "memory");
    __builtin_amdgcn_s_barrier();
    if (t + 2 < 32) {
      stageB(cur, t + 2);
      asm volatile("s_waitcnt vmcnt(4)" ::: "memory");
      __builtin_amdgcn_s_barrier();
    } else if (t + 1 < 32) {
      asm volatile("s_waitcnt vmcnt(0)" ::: "memory");
      __builtin_amdgcn_s_barrier();
    }
  }
#pragma unroll
  for (int i = 0; i < 2; ++i) {
    const int gm0 = m0 + i * 16 + (lane >> 4) * 4;
#pragma unroll
    for (int j = 0; j < 2; ++j) {
      const int gn = n0 + wc + j * 16 + (lane & 15);
      const float bv = bias[gn];
#pragma unroll
      for (int r = 0; r < 4; ++r) {
        const int gm = gm0 + r;
        if (gm < N_) {
          const size_t oo = (size_t)(b * N_ + gm) * 256 + gn;
          const float v = xin[oo] + fmaxf(acc[i][j][r] * 0.125f + bv, 0.f);
          xout[oo] = v;
          xoutB[oo] = f2bf(v);
        }
      }
    }
  }
}

// ================= fused encoder attention (unchanged) =================
__global__ __launch_bounds__(256) void attn_fused(
    const u16* __restrict__ qkvB, const unsigned* __restrict__ adjW,
    u16* __restrict__ ctxB) {
  __shared__ __align__(16) u16 K_lds[208 * 40];
  __shared__ __align__(16) u16 V_lds[32 * 232];
  __shared__ __align__(16) u16 P_lds[4][16 * 232];
  const int Lx = blockIdx.x;
  const int b = (Lx & 7) + 8 * (Lx >> 6);
  const int h = (Lx >> 3) & 7;
  const int tid = threadIdx.x, lane = tid & 63, wid = tid >> 6;
  const u16* qb = qkvB + (size_t)b * 200 * 768;
  for (int e = tid; e < 200 * 32; e += 256) {
    const int kv = e >> 5, d = e & 31;
    K_lds[kv * 40 + d] = qb[(size_t)kv * 768 + 256 + h * 32 + d];
    V_lds[d * 232 + kv] = qb[(size_t)kv * 768 + 512 + h * 32 + d];
  }
  for (int e = tid; e < 32 * 24; e += 256) V_lds[(e / 24) * 232 + 200 + (e % 24)] = 0;
  const int g = lane >> 4, c = lane & 15;
  u16* Pw = P_lds[wid];
  for (int e = lane; e < 16 * 16; e += 64) Pw[(e >> 4) * 232 + 208 + (e & 15)] = 0;
  __syncthreads();
  short8 kf[13];
#pragma unroll
  for (int nt = 0; nt < 13; ++nt)
    kf[nt] = *(const short8*)&K_lds[(nt * 16 + c) * 40 + g * 8];
  const float scale = 0.17677669529663687f;
  for (int t = 0; t < 4; ++t) {
    const int m0 = (wid * 4 + t) * 16;
    int qrow = b * 200 + m0 + c;
    if (qrow > BN_ - 1) qrow = BN_ - 1;
    const short8 qf = *(const short8*)&qkvB[(size_t)qrow * 768 + h * 32 + g * 8];
    f32x4 acc[13];
#pragma unroll
    for (int nt = 0; nt < 13; ++nt) {
      f32x4 z = {0.f, 0.f, 0.f, 0.f};
      acc[nt] = __builtin_amdgcn_mfma_f32_16x16x32_bf16(qf, kf[nt], z, 0, 0, 0);
    }
    unsigned m8[4][8];
#pragma unroll
    for (int r = 0; r < 4; ++r) {
      const uint4* mp = (const uint4*)(adjW + ((size_t)b * 256 + m0 + g * 4 + r) * 8);
      const uint4 a0 = mp[0], a1 = mp[1];
      m8[r][0] = a0.x; m8[r][1] = a0.y; m8[r][2] = a0.z; m8[r][3] = a0.w;
      m8[r][4] = a1.x; m8[r][5] = a1.y; m8[r][6] = a1.z; m8[r][7] = a1.w;
    }
    float mx[4] = {-3e38f, -3e38f, -3e38f, -3e38f};
#pragma unroll
    for (int nt = 0; nt < 13; ++nt) {
      const int col = nt * 16 + c;
      const float sentinel = (col < 200) ? -1e9f : -2e9f;
#pragma unroll
      for (int r = 0; r < 4; ++r) {
        const bool ok = (m8[r][nt >> 1] >> (((nt & 1) << 4) + c)) & 1u;
        const float v = ok ? acc[nt][r] * scale : sentinel;
        acc[nt][r] = v;
        mx[r] = fmaxf(mx[r], v);
      }
    }
#pragma unroll
    for (int off = 1; off < 16; off <<= 1)
#pragma unroll
      for (int r = 0; r < 4; ++r) mx[r] = fmaxf(mx[r], __shfl_xor(mx[r], off));
    float sm[4] = {0.f, 0.f, 0.f, 0.f};
#pragma unroll
    for (int nt = 0; nt < 13; ++nt)
#pragma unroll
      for (int r = 0; r < 4; ++r) {
        const float e = __expf(acc[nt][r] - mx[r]);
        acc[nt][r] = e;
        sm[r] += e;
      }
#pragma unroll
    for (int off = 1; off < 16; off <<= 1)
#pragma unroll
      for (int r = 0; r < 4; ++r) sm[r] += __shfl_xor(sm[r], off);
#pragma unroll
    for (int r = 0; r < 4; ++r) sm[r] = 1.f / sm[r];
#pragma unroll
    for (int nt = 0; nt < 13; ++nt)
#pragma unroll
      for (int r = 0; r < 4; ++r)
        Pw[(g * 4 + r) * 232 + nt * 16 + c] = f2bf(acc[nt][r] * sm[r]);
    f32x4 o0 = {0.f, 0.f, 0.f, 0.f}, o1 = {0.f, 0.f, 0.f, 0.f};
#pragma unroll
    for (int kt = 0; kt < 7; ++kt) {
      const short8 pf = *(const short8*)&Pw[c * 232 + kt * 32 + g * 8];
      const short8 v0 = *(const short8*)&V_lds[c * 232 + kt * 32 + g * 8];
      const short8 v1 = *(const short8*)&V_lds[(16 + c) * 232 + kt * 32 + g * 8];
      o0 = __builtin_amdgcn_mfma_f32_16x16x32_bf16(pf, v0, o0, 0, 0, 0);
      o1 = __builtin_amdgcn_mfma_f32_16x16x32_bf16(pf, v1, o1, 0, 0, 0);
    }
#pragma unroll
    for (int r = 0; r < 4; ++r) {
      const int q = m0 + g * 4 + r;
      if (q < N_) {
        u16* od = ctxB + ((size_t)(b * N_ + q)) * 256 + h * 32;
        od[c] = f2bf(o0[r]);
        od[16 + c] = f2bf(o1[r]);
      }
    }
  }
}

// adjW[b][row][w] = bitmask of adj[b][row][w*32..] > 0 (q-side mask, encoder)
__global__ __launch_bounds__(256) void adj_bits(const int* __restrict__ adj,
                                                unsigned* __restrict__ adjW) {
  const int b = blockIdx.x;
  for (int e = threadIdx.x; e < 256 * 8; e += 256) {
    const int row = e >> 3, w = e & 7;
    unsigned bits = 0u;
    if (row < N_ && w < 7) {
      const int base = w * 32;
      const int lim = (N_ - base) < 32 ? (N_ - base) : 32;
      const int* ar = adj + ((size_t)b * N_ + row) * N_ + base;
      for (int i = 0; i < lim; ++i) bits |= (ar[i] > 0 ? 1u : 0u) << i;
    }
    adjW[((size_t)b * 256 + row) * 8 + w] = bits;
  }
}

// adjTW[b][j][w] = bitmask over sources i of adjT[b][j][i] > 0, WITH self-loop bit.
__global__ __launch_bounds__(256) void adj_bits2(const int* __restrict__ adjT,
                                                 unsigned* __restrict__ adjTW) {
  const int b = blockIdx.x;
  for (int e = threadIdx.x; e < 256 * 8; e += 256) {
    const int j = e >> 3, w = e & 7;
    unsigned bits = 0u;
    if (j < N_ && w < 7) {
      const int base = w * 32;
      const int lim = (N_ - base) < 32 ? (N_ - base) : 32;
      const int* ar = adjT + ((size_t)b * N_ + j) * N_ + base;
      for (int i = 0; i < lim; ++i) bits |= (ar[i] > 0 ? 1u : 0u) << i;
      if (j >= base && j < base + 32) bits |= 1u << (j - base);
    }
    adjTW[((size_t)b * 256 + j) * 8 + w] = bits;
  }
}

__global__ __launch_bounds__(256) void adj_transpose(const int* __restrict__ adj,
                                                     int* __restrict__ adjT) {
  __shared__ int s[32][33];
  const int b = blockIdx.z;
  const int i0 = blockIdx.x * 32, j0 = blockIdx.y * 32;
  const int tx = threadIdx.x & 31, ty = threadIdx.x >> 5;
#pragma unroll
  for (int u = 0; u < 4; ++u) {
    const int i = i0 + ty + 8 * u, j = j0 + tx;
    if (i < N_ && j < N_) s[ty + 8 * u][tx] = adj[((size_t)b * N_ + i) * N_ + j];
  }
  __syncthreads();
#pragma unroll
  for (int u = 0; u < 4; ++u) {
    const int j = j0 + ty + 8 * u, i = i0 + tx;
    if (i < N_ && j < N_) adjT[((size_t)b * N_ + j) * N_ + i] = s[tx][ty + 8 * u];
  }
}

// ================= weight prep =================
__device__ const int PREP_TBL[21][6] = {
    {0, 0, 0, 0, 256, 2048},
    {0, 524288, 0, 524288, 256, 2048},
    {1, 0 * 65536, 1, 0, 256, 256},      {1, 1 * 65536, 1, 65536, 256, 256},
    {1, 2 * 65536, 1, 131072, 256, 256}, {1, 4 * 65536, 1, 196608, 256, 256},
    {1, 5 * 65536, 1, 262144, 256, 256}, {1, 6 * 65536, 1, 327680, 256, 256},
    {1, 8 * 65536, 1, 393216, 256, 256}, {1, 9 * 65536, 1, 458752, 256, 256},
    {1, 10 * 65536, 1, 524288, 256, 256},
    {1, 3 * 65536, 2, 0, 256, 256},      {1, 7 * 65536, 2, 65536, 256, 256},
    {1, 11 * 65536, 2, 131072, 256, 256},
    {2, 0, 3, 0, 256, 512}, {2, 131072, 3, 131072, 256, 512}, {2, 262144, 3, 262144, 256, 512},
    {3, 0, 4, 0, 512, 256}, {3, 131072, 4, 131072, 512, 256}, {3, 262144, 4, 262144, 512, 256},
    {4, 0, 5, 0, 256, 256},
};

__global__ __launch_bounds__(256) void prep_weights(
    const float* __restrict__ gat_W, const float* __restrict__ attn_W,
    const float* __restrict__ W1, const float* __restrict__ W2,
    const float* __restrict__ Wref, u16* __restrict__ gatWT, u16* __restrict__ WqkvT,
    u16* __restrict__ WoT, u16* __restrict__ W1T, u16* __restrict__ W2T,
    u16* __restrict__ WrefT) {
  const int mi = blockIdx.y;
  const int R = PREP_TBL[mi][4], C = PREP_TBL[mi][5];
  const int tc = C / 32;
  const int tiles = (R / 32) * tc;
  if ((int)blockIdx.x >= tiles) return;
  const int sel = PREP_TBL[mi][0], dsel = PREP_TBL[mi][2];
  const float* sp = (sel == 0) ? gat_W : (sel == 1) ? attn_W : (sel == 2) ? W1 : (sel == 3) ? W2 : Wref;
  u16* dp = (dsel == 0) ? gatWT : (dsel == 1) ? WqkvT : (dsel == 2) ? WoT : (dsel == 3) ? W1T
            : (dsel == 4) ? W2T : WrefT;
  sp += PREP_TBL[mi][1];
  dp += PREP_TBL[mi][3];
  const int r0 = (blockIdx.x / tc) * 32, c0 = (blockIdx.x % tc) * 32;
  __shared__ float s[32][33];
  const int tx = threadIdx.x & 31, ty = threadIdx.x >> 5;
#pragma unroll
  for (int u = 0; u < 4; ++u) s[ty + 8 * u][tx] = sp[(size_t)(r0 + ty + 8 * u) * C + c0 + tx];
  __syncthreads();
#pragma unroll
  for (int u = 0; u < 4; ++u)
    dp[(size_t)(c0 + ty + 8 * u) * R + r0 + tx] = f2bf(s[tx][ty + 8 * u]);
}

__global__ __launch_bounds__(256) void cast_bf16(const float* __restrict__ in,
                                                 u16* __restrict__ out, int n4) {
  const int i = blockIdx.x * 256 + threadIdx.x;
  if (i >= n4) return;
  const float4 v = ((const float4*)in)[i];
  ushort4 o;
  o.x = f2bf(v.x); o.y = f2bf(v.y); o.z = f2bf(v.z); o.w = f2bf(v.w);
  ((ushort4*)out)[i] = o;
}

// ================= fused GAT attvec + softmax stats =================
__global__ __launch_bounds__(256) void gat_attvec_stats(
    const u16* __restrict__ xpT, const float* __restrict__ att_src,
    const float* __restrict__ att_dst, const unsigned* __restrict__ adjTW,
    float* __restrict__ asrcH, float4* __restrict__ statsH) {
  __shared__ float as_l[256];
  __shared__ float ad_l[256];
  const int bh = blockIdx.x;
  const int b = bh >> 3, h = bh & 7;
  const int i = threadIdx.x;
  const u16* base = xpT + (size_t)bh * 65536 + i;
  const float* vs = att_src + h * 256;
  const float* vd = att_dst + h * 256;
  float ps = 0.f, pd = 0.f;
  for (int d = 0; d < 256; ++d) {
    const float x = bf2f(base[(size_t)d * 256]);
    ps += x * vs[d];
    pd += x * vd[d];
  }
  as_l[i] = ps;
  ad_l[i] = pd;
  asrcH[bh * 256 + i] = ps;
  __syncthreads();
  const int j = i;
  if (j < N_) {
    unsigned wbits[7];
#pragma unroll
    for (int w = 0; w < 7; ++w) wbits[w] = adjTW[((size_t)b * 256 + j) * 8 + w];
    const float ad = ad_l[j];
    float mx = -1e30f;
#pragma unroll
    for (int w = 0; w < 7; ++w) {
      const unsigned bits = wbits[w];
      for (int t = 0; t < 32; ++t) {
        float x = ad + as_l[w * 32 + t];
        x = fmaxf(x, 0.2f * x);
        x = ((bits >> t) & 1u) ? x : -1e9f;
        mx = fmaxf(mx, x);
      }
    }
    float sum = 0.f;
#pragma unroll
    for (int w = 0; w < 7; ++w) {
      const unsigned bits = wbits[w];
      for (int t = 0; t < 32; ++t) {
        float x = ad + as_l[w * 32 + t];
        x = fmaxf(x, 0.2f * x);
        x = ((bits >> t) & 1u) ? x : -1e9f;
        sum += __expf(x - mx);
      }
    }
    statsH[(size_t)bh * 256 + j] = make_float4(ad, mx, 1.f / sum, 0.f);
  }
}

// ================= LayerNorm (post-GAT only) =================
__global__ __launch_bounds__(256) void ln_pre_kernel(
    const float* __restrict__ in1, const float* __restrict__ in2,
    const float* __restrict__ sb, float* __restrict__ out, u16* __restrict__ outB) {
  const int row = blockIdx.x, t = threadIdx.x;
  const long o = (long)row * 256 + t;
  const float v = in1[o] + fmaxf(in2[o], 0.f);
  float s = v, q = v * v;
#pragma unroll
  for (int off = 32; off; off >>= 1) {
    s += __shfl_xor(s, off);
    q += __shfl_xor(q, off);
  }
  __shared__ float sh[8];
  const int wid = t >> 6, lane = t & 63;
  if (lane == 0) {
    sh[wid] = s;
    sh[4 + wid] = q;
  }
  __syncthreads();
  const float S = sh[0] + sh[1] + sh[2] + sh[3];
  const float Q = sh[4] + sh[5] + sh[6] + sh[7];
  const float mean = S * (1.f / 256.f);
  const float var = Q * (1.f / 256.f) - mean * mean;
  const float r = rsqrtf(var + 1e-5f);
  const float y = (v - mean) * r * sb[t] + sb[256 + t];
  out[o] = y;
  outB[o] = f2bf(y);
}

// ================= LSTM + pointer =================
__global__ __launch_bounds__(256) void lstm_gates(
    const float* __restrict__ di, const float* __restrict__ dh,
    const float* __restrict__ Wih, const float* __restrict__ Whh,
    const float* __restrict__ bias, float* __restrict__ gates) {
  const int idx = blockIdx.x * 256 + threadIdx.x;
  const int b = idx >> 10, n = idx & 1023;
  const float4* w1 = (const float4*)(Wih + (size_t)n * 256);
  const float4* w2 = (const float4*)(Whh + (size_t)n * 256);
  const float4* x1 = (const float4*)(di + b * 256);
  const float4* x2 = (const float4*)(dh + b * 256);
  float s = bias[n];
  for (int k = 0; k < 64; ++k) {
    const float4 a = x1[k], wv = w1[k];
    const float4 a2 = x2[k], wv2 = w2[k];
    s += a.x * wv.x + a.y * wv.y + a.z * wv.z + a.w * wv.w;
    s += a2.x * wv2.x + a2.y * wv2.y + a2.z * wv2.z + a2.w * wv2.w;
  }
  gates[idx] = s;
}

__global__ __launch_bounds__(256) void lstm_ew(
    const float* __restrict__ gates, const float* __restrict__ dc,
    float* __restrict__ h_out, float* __restrict__ c_out) {
  const int idx = blockIdx.x * 256 + threadIdx.x;
  const int b = idx >> 8, d = idx & 255;
  const float ig = sigmoidf_(gates[b * 1024 + d]);
  const float fg = sigmoidf_(gates[b * 1024 + 256 + d]);
  const float gg = tanhf(gates[b * 1024 + 512 + d]);
  const float og = sigmoidf_(gates[b * 1024 + 768 + d]);
  const float c = fg * dc[idx] + ig * gg;
  c_out[idx] = c;
  h_out[idx] = og * tanhf(c);
}

__global__ __launch_bounds__(256) void hq_gemm(
    const float* __restrict__ h, const float* __restrict__ Wq, float* __restrict__ hq) {
  const int b = blockIdx.x;
  const int n = threadIdx.x;
  float s = 0.f;
  for (int k = 0; k < 256; ++k) s += h[b * 256 + k] * Wq[k * 256 + n];
  hq[b * 256 + n] = s;
}

__global__ __launch_bounds__(64) void ptr_u(
    const float* __restrict__ pref, const float* __restrict__ hq,
    const float* __restrict__ pv, float* __restrict__ u) {
  const int row = blockIdx.x;
  const int b = row / N_;
  const int lane = threadIdx.x;
  float s = 0.f;
  for (int d = lane; d < 256; d += 64)
    s += tanhf(pref[(long)row * 256 + d] + hq[b * 256 + d]) * pv[d];
  s = wave_sum64(s);
  if (lane == 0) u[row] = s;
}

__global__ __launch_bounds__(256) void policy_softmax(
    const float* __restrict__ u, const int* __restrict__ mask, float* __restrict__ pol) {
  const int b = blockIdx.x, t = threadIdx.x;
  float val = -1e30f;
  if (t < N_) val = (mask[b * N_ + t] > 0) ? u[b * N_ + t] : -1e9f;
  float m = val;
#pragma unroll
  for (int off = 32; off; off >>= 1) m = fmaxf(m, __shfl_xor(m, off));
  __shared__ float sh[8];
  const int wid = t >> 6, lane = t & 63;
  if (lane == 0) sh[wid] = m;
  __syncthreads();
  m = fmaxf(fmaxf(sh[0], sh[1]), fmaxf(sh[2], sh[3]));
  const float e = (t < N_) ? __expf(val - m) : 0.f;
  float s = e;
#pragma unroll
  for (int off = 32; off; off >>= 1) s += __shfl_xor(s, off);
  __syncthreads();
  if (lane == 0) sh[4 + wid] = s;
  __syncthreads();
  const float S = sh[4] + sh[5] + sh[6] + sh[7];
  if (t < N_) pol[b * N_ + t] = e / S;
}

extern "C" void kernel_launch(void* const* d_in, const int* in_sizes, int n_in,
                              void* d_out, int out_size, void* d_ws, size_t ws_size,
                              hipStream_t stream) {
  const float* enc_inputs = (const float*)d_in[0];
  const float* dec_input = (const float*)d_in[1];
  const float* dec_h = (const float*)d_in[2];
  const float* dec_c = (const float*)d_in[3];
  const float* gat_W = (const float*)d_in[4];
  const float* gat_att_src = (const float*)d_in[5];
  const float* gat_att_dst = (const float*)d_in[6];
  const float* gat_bias = (const float*)d_in[7];
  const float* gat_ln = (const float*)d_in[8];
  const float* enc_attn_W = (const float*)d_in[9];
  const float* enc_attn_b = (const float*)d_in[10];
  const float* enc_ln1 = (const float*)d_in[11];
  const float* enc_ffn_W1 = (const float*)d_in[12];
  const float* enc_ffn_b1 = (const float*)d_in[13];
  const float* enc_ffn_W2 = (const float*)d_in[14];
  const float* enc_ffn_b2 = (const float*)d_in[15];
  const float* enc_ln2 = (const float*)d_in[16];
  const float* lstm_Wih = (const float*)d_in[17];
  const float* lstm_Whh = (const float*)d_in[18];
  const float* lstm_b = (const float*)d_in[19];
  const float* ptr_Wref = (const float*)d_in[20];
  const float* ptr_Wq = (const float*)d_in[21];
  const float* ptr_v = (const float*)d_in[22];
  const int* adj = (const int*)d_in[23];
  const int* mask = (const int*)d_in[24];

  float* out = (float*)d_out;
  float* policy = out;                       // 12800
  float* h_out = out + 12800;                // 16384
  float* c_out = out + 12800 + 16384;        // 16384
  float* emb = out + 12800 + 16384 + 16384;  // 3,276,800

  // ---- workspace layout ----
  char* ws = (char*)d_ws;
  char* arena = ws;  // 134,217,728 B phase-overlaid
  size_t o = 134217728;
  float* xbuf = (float*)(ws + o); o += 13107200;
  float* gates = (float*)(ws + o); o += 262144;
  float* hq = (float*)(ws + o); o += 65536;
  float* ubuf = (float*)(ws + o); o += 51200;
  u16* encB = (u16*)(ws + o); o += 6553600;
  u16* xbufB = (u16*)(ws + o); o += 6553600;
  u16* embB = (u16*)(ws + o); o += 6553600;
  int* adjT = (int*)(ws + o); o += 10240000;
  unsigned* adjW = (unsigned*)(ws + o); o += 524288;
  unsigned* adjTW = (unsigned*)(ws + o); o += 524288;
  float* asrcH = (float*)(ws + o); o += 524288;
  float4* statsH = (float4*)(ws + o); o += 2097152;
  u16* gatWT = (u16*)(ws + o); o += 2097152;
  u16* WqkvT = (u16*)(ws + o); o += 1179648;
  u16* WoT = (u16*)(ws + o); o += 393216;
  u16* W1T = (u16*)(ws + o); o += 786432;
  u16* W2T = (u16*)(ws + o); o += 786432;
  u16* WrefT = (u16*)(ws + o); o += 131072;
  if (ws_size < o) fprintf(stderr, "kernel_launch: ws too small (%zu < %zu)\n", ws_size, o);
  // GAT-phase arena views
  u16* xpT = (u16*)arena;                // [B][8][256][256] bf16 (67,108,864 B)
  // encoder-phase arena views
  u16* qkvB = (u16*)arena;               // [BN][768] bf16
  u16* ctxB = (u16*)(arena + 19660800);  // [BN][256] bf16
  u16* ffnB = (u16*)(arena + 26214400);  // [BN][512] bf16
  float* pref = (float*)arena;           // pointer phase

  // ---- prep ----
  prep_weights<<<dim3(512, 21), 256, 0, stream>>>(gat_W, enc_attn_W, enc_ffn_W1, enc_ffn_W2,
                                                  ptr_Wref, gatWT, WqkvT, WoT, W1T, W2T, WrefT);
  cast_bf16<<<3200, 256, 0, stream>>>(enc_inputs, encB, 819200);
  adj_transpose<<<dim3(7, 7, 64), 256, 0, stream>>>(adj, adjT);
  adj_bits<<<64, 256, 0, stream>>>(adj, adjW);
  adj_bits2<<<64, 256, 0, stream>>>(adjT, adjTW);

  // ---- GAT stack ----
  for (int g = 0; g < G_; ++g) {
    const u16* actB = (g == 0) ? encB : xbufB;
    const float* xin = (g == 0) ? enc_inputs : xbuf;
    gat_projT<<<dim3(16, 2, 64), 256, 0, stream>>>(gatWT + (size_t)g * 524288, actB, xpT);
    gat_attvec_stats<<<512, 256, 0, stream>>>(xpT, gat_att_src + g * 2048,
                                              gat_att_dst + g * 2048, adjTW, asrcH, statsH);
    gat_msg_mfma<<<896, 256, 0, stream>>>(xpT, asrcH, statsH, adjTW, gat_bias + g * H_,
                                          xin, xbuf, xbufB);
  }
  ln_pre_kernel<<<BN_, 256, 0, stream>>>(enc_inputs, xbuf, gat_ln, emb, embB);

  // ---- Transformer encoder ----
  for (int l = 0; l < L_; ++l) {
    gemm_bf16<0, true, false, true><<<dim3(100, 6), 256, 0, stream>>>(
        embB, WqkvT + (size_t)l * 196608, enc_attn_b + l * 1024, nullptr, nullptr, qkvB,
        BN_, 768, 256);
    attn_fused<<<512, 256, 0, stream>>>(qkvB, adjW, ctxB);
    gemm_ln<256><<<200, 256, 0, stream>>>(ctxB, WoT + (size_t)l * 65536,
                                          enc_attn_b + l * 1024 + 768, emb,
                                          enc_ln1 + l * 512, emb, embB);
    gemm_bf16<1, true, false, true><<<dim3(100, 4), 256, 0, stream>>>(
        embB, W1T + (size_t)l * 131072, enc_ffn_b1 + l * 512, nullptr, nullptr, ffnB,
        BN_, 512, 256);
    gemm_ln<512><<<200, 256, 0, stream>>>(ffnB, W2T + (size_t)l * 131072,
                                          enc_ffn_b2 + l * 256, emb,
                                          enc_ln2 + l * 512, emb, embB);
  }

  // ---- LSTM + pointer ----
  lstm_gates<<<256, 256, 0, stream>>>(dec_input, dec_h, lstm_Wih, lstm_Whh, lstm_b, gates);
  lstm_ew<<<64, 256, 0, stream>>>(gates, dec_c, h_out, c_out);
  hq_gemm<<<64, 256, 0, stream>>>(h_out, ptr_Wq, hq);
  gemm_bf16<0, false, false, false><<<dim3(100, 2), 256, 0, stream>>>(
      embB, WrefT, nullptr, nullptr, pref, nullptr, BN_, 256, 256);
  ptr_u<<<BN_, 64, 0, stream>>>(pref, hq, ptr_v, ubuf);
  policy_softmax<<<B_, 256, 0, stream>>>(ubuf, mask, policy);
}

// Round 14
// 565.994 us; speedup vs baseline: 1.0926x; 1.0926x over previous
//
#include <hip/hip_runtime.h>
#include <cstdio>
#include <math.h>

static constexpr int B_ = 64, N_ = 200, H_ = 256, NH_ = 8, G_ = 2, L_ = 3, F_ = 512;
static constexpr int BN_ = B_ * N_;  // 12800

typedef unsigned short u16;
typedef __attribute__((ext_vector_type(8))) short short8;
typedef __attribute__((ext_vector_type(4))) float f32x4;

#define LDSP(p) ((__attribute__((address_space(3))) unsigned int*)(p))
#define GLBP(p) ((const __attribute__((address_space(1))) unsigned int*)(p))

__device__ __forceinline__ float wave_sum64(float v) {
#pragma unroll
  for (int off = 32; off; off >>= 1) v += __shfl_xor(v, off);
  return v;
}
__device__ __forceinline__ float sigmoidf_(float x) { return 1.f / (1.f + __expf(-x)); }
__device__ __forceinline__ u16 f2bf(float x) {  // RNE f32->bf16
  unsigned u = __float_as_uint(x);
  return (u16)((u + 0x7FFFu + ((u >> 16) & 1u)) >> 16);
}
__device__ __forceinline__ float bf2f(u16 x) { return __uint_as_float((unsigned)x << 16); }

// ================= bf16 MFMA GEMM =================
// C[M][Nn] = act(A @ Bt^T + bias + res). A: bf16 [M][K]; Bt: bf16 [Nn][K].
template <int ACT, bool HAS_BIAS, bool HAS_RES, bool OUT_BF>
__global__ __launch_bounds__(256) void gemm_bf16(
    const u16* __restrict__ A, const u16* __restrict__ Bt,
    const float* __restrict__ bias, const float* __restrict__ res,
    float* __restrict__ Cf, u16* __restrict__ Cb, int M, int Nn, int K) {
  __shared__ u16 As[128 * 64];
  __shared__ u16 Bs[128 * 64];
  char* asB = (char*)As;
  char* bsB = (char*)Bs;
  const int tid = threadIdx.x;
  const int m0 = blockIdx.x * 128, n0 = blockIdx.y * 128;
  const int lane = tid & 63;
  const int wid = tid >> 6;
  const int wr = (wid >> 1) * 64, wc = (wid & 1) * 64;
  const int Kb = K * 2;
  const char* Ab = (const char*)A + (size_t)m0 * Kb;
  const char* Bb = (const char*)Bt + (size_t)n0 * Kb;
  f32x4 acc[4][4];
#pragma unroll
  for (int i = 0; i < 4; ++i)
#pragma unroll
    for (int j = 0; j < 4; ++j)
#pragma unroll
      for (int r = 0; r < 4; ++r) acc[i][j][r] = 0.f;

  for (int k0 = 0; k0 < K; k0 += 64) {
    if (k0) __syncthreads();
#pragma unroll
    for (int it = 0; it < 4; ++it) {
      const unsigned o = (unsigned)(it * 256 + tid) * 16;
      const int row = o >> 7;
      const unsigned bc = (o & 127u) ^ (unsigned)((row & 7) << 4);
      const unsigned wb = o & ~1023u;
      __builtin_amdgcn_global_load_lds(GLBP(Ab + (size_t)row * Kb + k0 * 2 + bc),
                                       LDSP(asB + wb), 16, 0, 0);
      __builtin_amdgcn_global_load_lds(GLBP(Bb + (size_t)row * Kb + k0 * 2 + bc),
                                       LDSP(bsB + wb), 16, 0, 0);
    }
    __syncthreads();
#pragma unroll
    for (int kk = 0; kk < 2; ++kk) {
      short8 aF[4], bF[4];
#pragma unroll
      for (int i = 0; i < 4; ++i) {
        const int ar = wr + i * 16 + (lane & 15);
        const unsigned ac = (unsigned)(kk * 64 + (lane >> 4) * 16) ^ (unsigned)((ar & 7) << 4);
        aF[i] = *(const short8*)(asB + ar * 128 + ac);
        const int br = wc + i * 16 + (lane & 15);
        const unsigned bc2 = (unsigned)(kk * 64 + (lane >> 4) * 16) ^ (unsigned)((br & 7) << 4);
        bF[i] = *(const short8*)(bsB + br * 128 + bc2);
      }
#pragma unroll
      for (int i = 0; i < 4; ++i)
#pragma unroll
        for (int j = 0; j < 4; ++j)
          acc[i][j] = __builtin_amdgcn_mfma_f32_16x16x32_bf16(aF[i], bF[j], acc[i][j], 0, 0, 0);
    }
  }
#pragma unroll
  for (int i = 0; i < 4; ++i) {
    const int gm0 = m0 + wr + i * 16 + (lane >> 4) * 4;
#pragma unroll
    for (int j = 0; j < 4; ++j) {
      const int gn = n0 + wc + j * 16 + (lane & 15);
      const float bv = HAS_BIAS ? bias[gn] : 0.f;
#pragma unroll
      for (int r = 0; r < 4; ++r) {
        const int gm = gm0 + r;
        float v = acc[i][j][r] + bv;
        if (HAS_RES) v += res[(size_t)gm * Nn + gn];
        if (ACT == 1) v = fmaxf(v, 0.f);
        if (OUT_BF)
          Cb[(size_t)gm * Nn + gn] = f2bf(v);
        else
          Cf[(size_t)gm * Nn + gn] = v;
      }
    }
  }
}

// ================= fused GEMM(+bias+res) + LayerNorm, Nn=256, pipelined =====
template <int K>
__global__ __launch_bounds__(256) void gemm_ln(
    const u16* __restrict__ A, const u16* __restrict__ Bt,
    const float* __restrict__ bias, const float* __restrict__ res,
    const float* __restrict__ sb, float* __restrict__ out, u16* __restrict__ outB) {
  __shared__ u16 As[2][64 * 64];
  __shared__ u16 Bs[2][256 * 64];
  __shared__ float2 red[64][4];
  const int tid = threadIdx.x;
  const int m0 = blockIdx.x * 64;
  const int lane = tid & 63, wid = tid >> 6;
  const int wc = wid * 64;
  const int Kb = K * 2;
  const char* Ab = (const char*)A + (size_t)m0 * Kb;
  const char* Bb = (const char*)Bt;
  constexpr int T = K / 64;
  f32x4 acc[4][4];
#pragma unroll
  for (int i = 0; i < 4; ++i)
#pragma unroll
    for (int j = 0; j < 4; ++j)
#pragma unroll
      for (int r = 0; r < 4; ++r) acc[i][j][r] = 0.f;

  auto stage = [&](int buf, int k0) {  // 10 vm ops per thread
#pragma unroll
    for (int it = 0; it < 2; ++it) {
      const unsigned o = (unsigned)(it * 256 + tid) * 16;
      const int row = o >> 7;
      const unsigned bc = (o & 127u) ^ (unsigned)((row & 7) << 4);
      const unsigned wb = o & ~1023u;
      __builtin_amdgcn_global_load_lds(GLBP(Ab + (size_t)row * Kb + k0 * 2 + bc),
                                       LDSP((char*)As[buf] + wb), 16, 0, 0);
    }
#pragma unroll
    for (int it = 0; it < 8; ++it) {
      const unsigned o = (unsigned)(it * 256 + tid) * 16;
      const int row = o >> 7;
      const unsigned bc = (o & 127u) ^ (unsigned)((row & 7) << 4);
      const unsigned wb = o & ~1023u;
      __builtin_amdgcn_global_load_lds(GLBP(Bb + (size_t)row * Kb + k0 * 2 + bc),
                                       LDSP((char*)Bs[buf] + wb), 16, 0, 0);
    }
  };

  stage(0, 0);
  stage(1, 64);
  asm volatile("s_waitcnt vmcnt(10)" ::: "memory");
  __builtin_amdgcn_s_barrier();

  for (int t = 0; t < T; ++t) {
    const int cur = t & 1;
    const char* asB = (const char*)As[cur];
    const char* bsB = (const char*)Bs[cur];
#pragma unroll
    for (int kk = 0; kk < 2; ++kk) {
      short8 aF[4], bF[4];
#pragma unroll
      for (int i = 0; i < 4; ++i) {
        const int ar = i * 16 + (lane & 15);
        const unsigned ac = (unsigned)(kk * 64 + (lane >> 4) * 16) ^ (unsigned)((ar & 7) << 4);
        aF[i] = *(const short8*)(asB + ar * 128 + ac);
        const int br = wc + i * 16 + (lane & 15);
        const unsigned bc2 = (unsigned)(kk * 64 + (lane >> 4) * 16) ^ (unsigned)((br & 7) << 4);
        bF[i] = *(const short8*)(bsB + br * 128 + bc2);
      }
#pragma unroll
      for (int i = 0; i < 4; ++i)
#pragma unroll
        for (int j = 0; j < 4; ++j)
          acc[i][j] = __builtin_amdgcn_mfma_f32_16x16x32_bf16(aF[i], bF[j], acc[i][j], 0, 0, 0);
    }
    asm volatile("s_waitcnt lgkmcnt(0)" ::: "memory");
    __builtin_amdgcn_s_barrier();
    if (t + 2 < T) {
      stage(cur, (t + 2) * 64);
      asm volatile("s_waitcnt vmcnt(10)" ::: "memory");
      __builtin_amdgcn_s_barrier();
    } else if (t + 1 < T) {
      asm volatile("s_waitcnt vmcnt(0)" ::: "memory");
      __builtin_amdgcn_s_barrier();
    }
  }
#pragma unroll
  for (int i = 0; i < 4; ++i) {
#pragma unroll
    for (int j = 0; j < 4; ++j) {
      const int gn = wc + j * 16 + (lane & 15);
      const float bv = bias[gn];
#pragma unroll
      for (int r = 0; r < 4; ++r) {
        const int gm = m0 + i * 16 + (lane >> 4) * 4 + r;
        acc[i][j][r] += bv + res[(size_t)gm * 256 + gn];
      }
    }
  }
#pragma unroll
  for (int i = 0; i < 4; ++i) {
#pragma unroll
    for (int r = 0; r < 4; ++r) {
      float s = 0.f, q = 0.f;
#pragma unroll
      for (int j = 0; j < 4; ++j) {
        const float v = acc[i][j][r];
        s += v;
        q += v * v;
      }
#pragma unroll
      for (int off = 1; off < 16; off <<= 1) {
        s += __shfl_xor(s, off);
        q += __shfl_xor(q, off);
      }
      if ((lane & 15) == 0) red[i * 16 + (lane >> 4) * 4 + r][wid] = make_float2(s, q);
    }
  }
  __syncthreads();
#pragma unroll
  for (int i = 0; i < 4; ++i) {
#pragma unroll
    for (int r = 0; r < 4; ++r) {
      const int row = i * 16 + (lane >> 4) * 4 + r;
      const float2 p0 = red[row][0], p1 = red[row][1], p2 = red[row][2], p3 = red[row][3];
      const float S = p0.x + p1.x + p2.x + p3.x;
      const float Q = p0.y + p1.y + p2.y + p3.y;
      const float mean = S * (1.f / 256.f);
      const float var = Q * (1.f / 256.f) - mean * mean;
      const float rstd = rsqrtf(var + 1e-5f);
      const int gm = m0 + row;
#pragma unroll
      for (int j = 0; j < 4; ++j) {
        const int gn = wc + j * 16 + (lane & 15);
        const float y = (acc[i][j][r] - mean) * rstd * sb[gn] + sb[256 + gn];
        out[(size_t)gm * 256 + gn] = y;
        outB[(size_t)gm * 256 + gn] = f2bf(y);
      }
    }
  }
}

// ================= GAT projection -> transposed slabs =================
__global__ __launch_bounds__(256) void gat_projT(
    const u16* __restrict__ Wt, const u16* __restrict__ actB, u16* __restrict__ xpT) {
  __shared__ u16 As[128 * 64];
  __shared__ u16 Bs[128 * 64];
  char* asB = (char*)As;
  char* bsB = (char*)Bs;
  const int tid = threadIdx.x;
  const int m0 = blockIdx.x * 128;
  const int n0 = blockIdx.y * 128;
  const int b = blockIdx.z;
  const int lane = tid & 63;
  const int wid = tid >> 6;
  const int wr = (wid >> 1) * 64, wc = (wid & 1) * 64;
  const char* Ab = (const char*)Wt + (size_t)m0 * 512;
  const char* Bb = (const char*)actB + ((size_t)b * 200 + n0) * 512;
  f32x4 acc[4][4];
#pragma unroll
  for (int i = 0; i < 4; ++i)
#pragma unroll
    for (int j = 0; j < 4; ++j)
#pragma unroll
      for (int r = 0; r < 4; ++r) acc[i][j][r] = 0.f;

  for (int k0 = 0; k0 < 256; k0 += 64) {
    if (k0) __syncthreads();
#pragma unroll
    for (int it = 0; it < 4; ++it) {
      const unsigned o = (unsigned)(it * 256 + tid) * 16;
      const int row = o >> 7;
      const unsigned bc = (o & 127u) ^ (unsigned)((row & 7) << 4);
      const unsigned wb = o & ~1023u;
      __builtin_amdgcn_global_load_lds(GLBP(Ab + (size_t)row * 512 + k0 * 2 + bc),
                                       LDSP(asB + wb), 16, 0, 0);
      __builtin_amdgcn_global_load_lds(GLBP(Bb + (size_t)row * 512 + k0 * 2 + bc),
                                       LDSP(bsB + wb), 16, 0, 0);
    }
    __syncthreads();
#pragma unroll
    for (int kk = 0; kk < 2; ++kk) {
      short8 aF[4], bF[4];
#pragma unroll
      for (int i = 0; i < 4; ++i) {
        const int ar = wr + i * 16 + (lane & 15);
        const unsigned ac = (unsigned)(kk * 64 + (lane >> 4) * 16) ^ (unsigned)((ar & 7) << 4);
        aF[i] = *(const short8*)(asB + ar * 128 + ac);
        const int br = wc + i * 16 + (lane & 15);
        const unsigned bc2 = (unsigned)(kk * 64 + (lane >> 4) * 16) ^ (unsigned)((br & 7) << 4);
        bF[i] = *(const short8*)(bsB + br * 128 + bc2);
      }
#pragma unroll
      for (int i = 0; i < 4; ++i)
#pragma unroll
        for (int j = 0; j < 4; ++j)
          acc[i][j] = __builtin_amdgcn_mfma_f32_16x16x32_bf16(aF[i], bF[j], acc[i][j], 0, 0, 0);
    }
  }
  u16* outb = xpT + (size_t)b * 524288;
#pragma unroll
  for (int i = 0; i < 4; ++i) {
    const int gm0 = m0 + wr + i * 16 + (lane >> 4) * 4;
#pragma unroll
    for (int j = 0; j < 4; ++j) {
      const int gn = n0 + wc + j * 16 + (lane & 15);
#pragma unroll
      for (int r = 0; r < 4; ++r) {
        const int gm = gm0 + r;
        outb[(size_t)gm * 256 + gn] = (gn < N_) ? f2bf(acc[i][j][r]) : (u16)0;
      }
    }
  }
}

// ================= GAT message MFMA v4 (R11 best: 32j x 256d, grid 448) ====
// out[b,j,d] = xin[b,j,d] + relu( (1/8) sum_{h,i} P[b,h,j,i]*xpT[b,h,d,i] + bias[d] )
__global__ __launch_bounds__(256) void gat_msg_mfma(
    const u16* __restrict__ xpT, const float* __restrict__ asrcH,
    const float4* __restrict__ statsH, const unsigned* __restrict__ adjTW,
    const float* __restrict__ bias, const float* __restrict__ xin,
    float* __restrict__ xout, u16* __restrict__ xoutB) {
  __shared__ u16 Bs[2][256 * 64];  // [d 256][k 64] swizzled (32 KB each)
  __shared__ u16 Ps[2][32 * 64];   // [j 32][i 64] swizzled (4 KB each)
  const int tid = threadIdx.x;
  const int Lx = blockIdx.x;           // 448, XCD-swizzled
  const int xcd = Lx & 7;
  const int slot = Lx >> 3;            // 0..55
  const int q = slot % 7;              // j-tile 0..6
  const int b = xcd + 8 * (slot / 7);  // batch: same-b blocks share one XCD
  const int m0 = q * 32;
  const int lane = tid & 63, wid = tid >> 6;
  const int wc = wid * 64;
  const char* baseB = (const char*)xpT + ((size_t)b << 20);
  f32x4 acc[2][4];
#pragma unroll
  for (int i = 0; i < 2; ++i)
#pragma unroll
    for (int j = 0; j < 4; ++j)
#pragma unroll
      for (int r = 0; r < 4; ++r) acc[i][j][r] = 0.f;

  auto stageB = [&](int buf, int t) {  // 8 vm ops per thread
    const size_t off = (size_t)(t >> 2) * 131072 + (size_t)((t & 3) * 128);
    char* bD = (char*)Bs[buf];
#pragma unroll
    for (int it = 0; it < 8; ++it) {
      const unsigned o = (unsigned)(it * 256 + tid) * 16;
      const int row = o >> 7;
      const unsigned bc = (o & 127u) ^ (unsigned)((row & 7) << 4);
      const unsigned wb = o & ~1023u;
      __builtin_amdgcn_global_load_lds(GLBP(baseB + off + (size_t)row * 512 + bc),
                                       LDSP(bD + wb), 16, 0, 0);
    }
  };
  auto computeP = [&](int buf, int t) {
    const int h = t >> 2, k0 = (t & 3) * 64;
    const size_t bh8 = ((size_t)(b * 8 + h)) << 8;
    const float* asp = asrcH + bh8 + k0;
    u16* P = Ps[buf];
    const int j = tid >> 3;
    const int ib = (tid & 7) << 3;
    const int gj = m0 + j;
    const int jc = gj < N_ ? gj : N_ - 1;
    const float4 st = statsH[bh8 + jc];
    const unsigned wbits =
        adjTW[((size_t)b * 256 + jc) * 8 + ((k0 + ib) >> 5)] >> ((k0 + ib) & 31);
    const float4 a0 = *(const float4*)(asp + ib);
    const float4 a1 = *(const float4*)(asp + ib + 4);
    const float av[8] = {a0.x, a0.y, a0.z, a0.w, a1.x, a1.y, a1.z, a1.w};
    float pv[8];
#pragma unroll
    for (int u = 0; u < 8; ++u) {
      float x = st.x + av[u];
      x = fmaxf(x, 0.2f * x);
      const float pe = __expf(x - st.y) * st.z;
      pv[u] = ((wbits >> u) & 1u) ? pe : 0.f;
    }
    unsigned pk[4];
#pragma unroll
    for (int qx = 0; qx < 4; ++qx)
      pk[qx] = (unsigned)f2bf(pv[2 * qx]) | ((unsigned)f2bf(pv[2 * qx + 1]) << 16);
    const unsigned ad2 =
        (unsigned)(j * 128) + (((unsigned)(ib * 2)) ^ (((unsigned)(j & 7)) << 4));
    *(uint4*)((char*)P + ad2) = make_uint4(pk[0], pk[1], pk[2], pk[3]);
  };

  stageB(0, 0);
  stageB(1, 1);
  computeP(0, 0);
  asm volatile("s_waitcnt lgkmcnt(0)" ::: "memory");
  asm volatile("s_waitcnt vmcnt(8)" ::: "memory");
  __builtin_amdgcn_s_barrier();

  for (int t = 0; t < 32; ++t) {
    const int cur = t & 1;
    if (t + 1 < 32) computeP(cur ^ 1, t + 1);
    const char* pB = (const char*)Ps[cur];
    const char* bB = (const char*)Bs[cur];
#pragma unroll
    for (int kk = 0; kk < 2; ++kk) {
      short8 aF[2], bF[4];
#pragma unroll
      for (int i = 0; i < 2; ++i) {
        const int ar = i * 16 + (lane & 15);
        const unsigned ac = (unsigned)(kk * 64 + (lane >> 4) * 16) ^ (unsigned)((ar & 7) << 4);
        aF[i] = *(const short8*)(pB + ar * 128 + ac);
      }
#pragma unroll
      for (int j = 0; j < 4; ++j) {
        const int br = wc + j * 16 + (lane & 15);
        const unsigned bc2 = (unsigned)(kk * 64 + (lane >> 4) * 16) ^ (unsigned)((br & 7) << 4);
        bF[j] = *(const short8*)(bB + br * 128 + bc2);
      }
#pragma unroll
      for (int i = 0; i < 2; ++i)
#pragma unroll
        for (int j = 0; j < 4; ++j)
          acc[i][j] = __builtin_amdgcn_mfma_f32_16x16x32_bf16(aF[i], bF[j], acc[i][j], 0, 0, 0);
    }
    asm volatile("s_waitcnt lgkmcnt(0)" ::: "memory");
    __builtin_amdgcn_s_barrier();
    if (t + 2 < 32) {
      stageB(cur, t + 2);
      asm volatile("s_waitcnt vmcnt(8)" ::: "memory");
      __builtin_amdgcn_s_barrier();
    } else if (t + 1 < 32) {
      asm volatile("s_waitcnt vmcnt(0)" ::: "memory");
      __builtin_amdgcn_s_barrier();
    }
  }
#pragma unroll
  for (int i = 0; i < 2; ++i) {
    const int gm0 = m0 + i * 16 + (lane >> 4) * 4;
#pragma unroll
    for (int j = 0; j < 4; ++j) {
      const int gn = wc + j * 16 + (lane & 15);
      const float bv = bias[gn];
#pragma unroll
      for (int r = 0; r < 4; ++r) {
        const int gm = gm0 + r;
        if (gm < N_) {
          const size_t oo = (size_t)(b * N_ + gm) * 256 + gn;
          const float v = xin[oo] + fmaxf(acc[i][j][r] * 0.125f + bv, 0.f);
          xout[oo] = v;
          xoutB[oo] = f2bf(v);
        }
      }
    }
  }
}

// ================= fused encoder attention (unchanged) =================
__global__ __launch_bounds__(256) void attn_fused(
    const u16* __restrict__ qkvB, const unsigned* __restrict__ adjW,
    u16* __restrict__ ctxB) {
  __shared__ __align__(16) u16 K_lds[208 * 40];
  __shared__ __align__(16) u16 V_lds[32 * 232];
  __shared__ __align__(16) u16 P_lds[4][16 * 232];
  const int Lx = blockIdx.x;
  const int b = (Lx & 7) + 8 * (Lx >> 6);
  const int h = (Lx >> 3) & 7;
  const int tid = threadIdx.x, lane = tid & 63, wid = tid >> 6;
  const u16* qb = qkvB + (size_t)b * 200 * 768;
  for (int e = tid; e < 200 * 32; e += 256) {
    const int kv = e >> 5, d = e & 31;
    K_lds[kv * 40 + d] = qb[(size_t)kv * 768 + 256 + h * 32 + d];
    V_lds[d * 232 + kv] = qb[(size_t)kv * 768 + 512 + h * 32 + d];
  }
  for (int e = tid; e < 32 * 24; e += 256) V_lds[(e / 24) * 232 + 200 + (e % 24)] = 0;
  const int g = lane >> 4, c = lane & 15;
  u16* Pw = P_lds[wid];
  for (int e = lane; e < 16 * 16; e += 64) Pw[(e >> 4) * 232 + 208 + (e & 15)] = 0;
  __syncthreads();
  short8 kf[13];
#pragma unroll
  for (int nt = 0; nt < 13; ++nt)
    kf[nt] = *(const short8*)&K_lds[(nt * 16 + c) * 40 + g * 8];
  const float scale = 0.17677669529663687f;
  for (int t = 0; t < 4; ++t) {
    const int m0 = (wid * 4 + t) * 16;
    int qrow = b * 200 + m0 + c;
    if (qrow > BN_ - 1) qrow = BN_ - 1;
    const short8 qf = *(const short8*)&qkvB[(size_t)qrow * 768 + h * 32 + g * 8];
    f32x4 acc[13];
#pragma unroll
    for (int nt = 0; nt < 13; ++nt) {
      f32x4 z = {0.f, 0.f, 0.f, 0.f};
      acc[nt] = __builtin_amdgcn_mfma_f32_16x16x32_bf16(qf, kf[nt], z, 0, 0, 0);
    }
    unsigned m8[4][8];
#pragma unroll
    for (int r = 0; r < 4; ++r) {
      const uint4* mp = (const uint4*)(adjW + ((size_t)b * 256 + m0 + g * 4 + r) * 8);
      const uint4 a0 = mp[0], a1 = mp[1];
      m8[r][0] = a0.x; m8[r][1] = a0.y; m8[r][2] = a0.z; m8[r][3] = a0.w;
      m8[r][4] = a1.x; m8[r][5] = a1.y; m8[r][6] = a1.z; m8[r][7] = a1.w;
    }
    float mx[4] = {-3e38f, -3e38f, -3e38f, -3e38f};
#pragma unroll
    for (int nt = 0; nt < 13; ++nt) {
      const int col = nt * 16 + c;
      const float sentinel = (col < 200) ? -1e9f : -2e9f;
#pragma unroll
      for (int r = 0; r < 4; ++r) {
        const bool ok = (m8[r][nt >> 1] >> (((nt & 1) << 4) + c)) & 1u;
        const float v = ok ? acc[nt][r] * scale : sentinel;
        acc[nt][r] = v;
        mx[r] = fmaxf(mx[r], v);
      }
    }
#pragma unroll
    for (int off = 1; off < 16; off <<= 1)
#pragma unroll
      for (int r = 0; r < 4; ++r) mx[r] = fmaxf(mx[r], __shfl_xor(mx[r], off));
    float sm[4] = {0.f, 0.f, 0.f, 0.f};
#pragma unroll
    for (int nt = 0; nt < 13; ++nt)
#pragma unroll
      for (int r = 0; r < 4; ++r) {
        const float e = __expf(acc[nt][r] - mx[r]);
        acc[nt][r] = e;
        sm[r] += e;
      }
#pragma unroll
    for (int off = 1; off < 16; off <<= 1)
#pragma unroll
      for (int r = 0; r < 4; ++r) sm[r] += __shfl_xor(sm[r], off);
#pragma unroll
    for (int r = 0; r < 4; ++r) sm[r] = 1.f / sm[r];
#pragma unroll
    for (int nt = 0; nt < 13; ++nt)
#pragma unroll
      for (int r = 0; r < 4; ++r)
        Pw[(g * 4 + r) * 232 + nt * 16 + c] = f2bf(acc[nt][r] * sm[r]);
    f32x4 o0 = {0.f, 0.f, 0.f, 0.f}, o1 = {0.f, 0.f, 0.f, 0.f};
#pragma unroll
    for (int kt = 0; kt < 7; ++kt) {
      const short8 pf = *(const short8*)&Pw[c * 232 + kt * 32 + g * 8];
      const short8 v0 = *(const short8*)&V_lds[c * 232 + kt * 32 + g * 8];
      const short8 v1 = *(const short8*)&V_lds[(16 + c) * 232 + kt * 32 + g * 8];
      o0 = __builtin_amdgcn_mfma_f32_16x16x32_bf16(pf, v0, o0, 0, 0, 0);
      o1 = __builtin_amdgcn_mfma_f32_16x16x32_bf16(pf, v1, o1, 0, 0, 0);
    }
#pragma unroll
    for (int r = 0; r < 4; ++r) {
      const int q = m0 + g * 4 + r;
      if (q < N_) {
        u16* od = ctxB + ((size_t)(b * N_ + q)) * 256 + h * 32;
        od[c] = f2bf(o0[r]);
        od[16 + c] = f2bf(o1[r]);
      }
    }
  }
}

// adjW[b][row][w] = bitmask of adj[b][row][w*32..] > 0 (q-side mask, encoder)
__global__ __launch_bounds__(256) void adj_bits(const int* __restrict__ adj,
                                                unsigned* __restrict__ adjW) {
  const int b = blockIdx.x;
  for (int e = threadIdx.x; e < 256 * 8; e += 256) {
    const int row = e >> 3, w = e & 7;
    unsigned bits = 0u;
    if (row < N_ && w < 7) {
      const int base = w * 32;
      const int lim = (N_ - base) < 32 ? (N_ - base) : 32;
      const int* ar = adj + ((size_t)b * N_ + row) * N_ + base;
      for (int i = 0; i < lim; ++i) bits |= (ar[i] > 0 ? 1u : 0u) << i;
    }
    adjW[((size_t)b * 256 + row) * 8 + w] = bits;
  }
}

// adjTW[b][j][w] = bitmask over sources i of adjT[b][j][i] > 0, WITH self-loop bit.
__global__ __launch_bounds__(256) void adj_bits2(const int* __restrict__ adjT,
                                                 unsigned* __restrict__ adjTW) {
  const int b = blockIdx.x;
  for (int e = threadIdx.x; e < 256 * 8; e += 256) {
    const int j = e >> 3, w = e & 7;
    unsigned bits = 0u;
    if (j < N_ && w < 7) {
      const int base = w * 32;
      const int lim = (N_ - base) < 32 ? (N_ - base) : 32;
      const int* ar = adjT + ((size_t)b * N_ + j) * N_ + base;
      for (int i = 0; i < lim; ++i) bits |= (ar[i] > 0 ? 1u : 0u) << i;
      if (j >= base && j < base + 32) bits |= 1u << (j - base);
    }
    adjTW[((size_t)b * 256 + j) * 8 + w] = bits;
  }
}

__global__ __launch_bounds__(256) void adj_transpose(const int* __restrict__ adj,
                                                     int* __restrict__ adjT) {
  __shared__ int s[32][33];
  const int b = blockIdx.z;
  const int i0 = blockIdx.x * 32, j0 = blockIdx.y * 32;
  const int tx = threadIdx.x & 31, ty = threadIdx.x >> 5;
#pragma unroll
  for (int u = 0; u < 4; ++u) {
    const int i = i0 + ty + 8 * u, j = j0 + tx;
    if (i < N_ && j < N_) s[ty + 8 * u][tx] = adj[((size_t)b * N_ + i) * N_ + j];
  }
  __syncthreads();
#pragma unroll
  for (int u = 0; u < 4; ++u) {
    const int j = j0 + ty + 8 * u, i = i0 + tx;
    if (i < N_ && j < N_) adjT[((size_t)b * N_ + j) * N_ + i] = s[tx][ty + 8 * u];
  }
}

// ================= weight prep =================
__device__ const int PREP_TBL[21][6] = {
    {0, 0, 0, 0, 256, 2048},
    {0, 524288, 0, 524288, 256, 2048},
    {1, 0 * 65536, 1, 0, 256, 256},      {1, 1 * 65536, 1, 65536, 256, 256},
    {1, 2 * 65536, 1, 131072, 256, 256}, {1, 4 * 65536, 1, 196608, 256, 256},
    {1, 5 * 65536, 1, 262144, 256, 256}, {1, 6 * 65536, 1, 327680, 256, 256},
    {1, 8 * 65536, 1, 393216, 256, 256}, {1, 9 * 65536, 1, 458752, 256, 256},
    {1, 10 * 65536, 1, 524288, 256, 256},
    {1, 3 * 65536, 2, 0, 256, 256},      {1, 7 * 65536, 2, 65536, 256, 256},
    {1, 11 * 65536, 2, 131072, 256, 256},
    {2, 0, 3, 0, 256, 512}, {2, 131072, 3, 131072, 256, 512}, {2, 262144, 3, 262144, 256, 512},
    {3, 0, 4, 0, 512, 256}, {3, 131072, 4, 131072, 512, 256}, {3, 262144, 4, 262144, 512, 256},
    {4, 0, 5, 0, 256, 256},
};

__global__ __launch_bounds__(256) void prep_weights(
    const float* __restrict__ gat_W, const float* __restrict__ attn_W,
    const float* __restrict__ W1, const float* __restrict__ W2,
    const float* __restrict__ Wref, u16* __restrict__ gatWT, u16* __restrict__ WqkvT,
    u16* __restrict__ WoT, u16* __restrict__ W1T, u16* __restrict__ W2T,
    u16* __restrict__ WrefT) {
  const int mi = blockIdx.y;
  const int R = PREP_TBL[mi][4], C = PREP_TBL[mi][5];
  const int tc = C / 32;
  const int tiles = (R / 32) * tc;
  if ((int)blockIdx.x >= tiles) return;
  const int sel = PREP_TBL[mi][0], dsel = PREP_TBL[mi][2];
  const float* sp = (sel == 0) ? gat_W : (sel == 1) ? attn_W : (sel == 2) ? W1 : (sel == 3) ? W2 : Wref;
  u16* dp = (dsel == 0) ? gatWT : (dsel == 1) ? WqkvT : (dsel == 2) ? WoT : (dsel == 3) ? W1T
            : (dsel == 4) ? W2T : WrefT;
  sp += PREP_TBL[mi][1];
  dp += PREP_TBL[mi][3];
  const int r0 = (blockIdx.x / tc) * 32, c0 = (blockIdx.x % tc) * 32;
  __shared__ float s[32][33];
  const int tx = threadIdx.x & 31, ty = threadIdx.x >> 5;
#pragma unroll
  for (int u = 0; u < 4; ++u) s[ty + 8 * u][tx] = sp[(size_t)(r0 + ty + 8 * u) * C + c0 + tx];
  __syncthreads();
#pragma unroll
  for (int u = 0; u < 4; ++u)
    dp[(size_t)(c0 + ty + 8 * u) * R + r0 + tx] = f2bf(s[tx][ty + 8 * u]);
}

__global__ __launch_bounds__(256) void cast_bf16(const float* __restrict__ in,
                                                 u16* __restrict__ out, int n4) {
  const int i = blockIdx.x * 256 + threadIdx.x;
  if (i >= n4) return;
  const float4 v = ((const float4*)in)[i];
  ushort4 o;
  o.x = f2bf(v.x); o.y = f2bf(v.y); o.z = f2bf(v.z); o.w = f2bf(v.w);
  ((ushort4*)out)[i] = o;
}

// ================= fused GAT attvec + softmax stats =================
__global__ __launch_bounds__(256) void gat_attvec_stats(
    const u16* __restrict__ xpT, const float* __restrict__ att_src,
    const float* __restrict__ att_dst, const unsigned* __restrict__ adjTW,
    float* __restrict__ asrcH, float4* __restrict__ statsH) {
  __shared__ float as_l[256];
  __shared__ float ad_l[256];
  const int bh = blockIdx.x;
  const int b = bh >> 3, h = bh & 7;
  const int i = threadIdx.x;
  const u16* base = xpT + (size_t)bh * 65536 + i;
  const float* vs = att_src + h * 256;
  const float* vd = att_dst + h * 256;
  float ps = 0.f, pd = 0.f;
  for (int d = 0; d < 256; ++d) {
    const float x = bf2f(base[(size_t)d * 256]);
    ps += x * vs[d];
    pd += x * vd[d];
  }
  as_l[i] = ps;
  ad_l[i] = pd;
  asrcH[bh * 256 + i] = ps;
  __syncthreads();
  const int j = i;
  if (j < N_) {
    unsigned wbits[7];
#pragma unroll
    for (int w = 0; w < 7; ++w) wbits[w] = adjTW[((size_t)b * 256 + j) * 8 + w];
    const float ad = ad_l[j];
    float mx = -1e30f;
#pragma unroll
    for (int w = 0; w < 7; ++w) {
      const unsigned bits = wbits[w];
      for (int t = 0; t < 32; ++t) {
        float x = ad + as_l[w * 32 + t];
        x = fmaxf(x, 0.2f * x);
        x = ((bits >> t) & 1u) ? x : -1e9f;
        mx = fmaxf(mx, x);
      }
    }
    float sum = 0.f;
#pragma unroll
    for (int w = 0; w < 7; ++w) {
      const unsigned bits = wbits[w];
      for (int t = 0; t < 32; ++t) {
        float x = ad + as_l[w * 32 + t];
        x = fmaxf(x, 0.2f * x);
        x = ((bits >> t) & 1u) ? x : -1e9f;
        sum += __expf(x - mx);
      }
    }
    statsH[(size_t)bh * 256 + j] = make_float4(ad, mx, 1.f / sum, 0.f);
  }
}

// ================= LayerNorm (post-GAT only) =================
__global__ __launch_bounds__(256) void ln_pre_kernel(
    const float* __restrict__ in1, const float* __restrict__ in2,
    const float* __restrict__ sb, float* __restrict__ out, u16* __restrict__ outB) {
  const int row = blockIdx.x, t = threadIdx.x;
  const long o = (long)row * 256 + t;
  const float v = in1[o] + fmaxf(in2[o], 0.f);
  float s = v, q = v * v;
#pragma unroll
  for (int off = 32; off; off >>= 1) {
    s += __shfl_xor(s, off);
    q += __shfl_xor(q, off);
  }
  __shared__ float sh[8];
  const int wid = t >> 6, lane = t & 63;
  if (lane == 0) {
    sh[wid] = s;
    sh[4 + wid] = q;
  }
  __syncthreads();
  const float S = sh[0] + sh[1] + sh[2] + sh[3];
  const float Q = sh[4] + sh[5] + sh[6] + sh[7];
  const float mean = S * (1.f / 256.f);
  const float var = Q * (1.f / 256.f) - mean * mean;
  const float r = rsqrtf(var + 1e-5f);
  const float y = (v - mean) * r * sb[t] + sb[256 + t];
  out[o] = y;
  outB[o] = f2bf(y);
}

// ================= LSTM + pointer =================
__global__ __launch_bounds__(256) void lstm_gates(
    const float* __restrict__ di, const float* __restrict__ dh,
    const float* __restrict__ Wih, const float* __restrict__ Whh,
    const float* __restrict__ bias, float* __restrict__ gates) {
  const int idx = blockIdx.x * 256 + threadIdx.x;
  const int b = idx >> 10, n = idx & 1023;
  const float4* w1 = (const float4*)(Wih + (size_t)n * 256);
  const float4* w2 = (const float4*)(Whh + (size_t)n * 256);
  const float4* x1 = (const float4*)(di + b * 256);
  const float4* x2 = (const float4*)(dh + b * 256);
  float s = bias[n];
  for (int k = 0; k < 64; ++k) {
    const float4 a = x1[k], wv = w1[k];
    const float4 a2 = x2[k], wv2 = w2[k];
    s += a.x * wv.x + a.y * wv.y + a.z * wv.z + a.w * wv.w;
    s += a2.x * wv2.x + a2.y * wv2.y + a2.z * wv2.z + a2.w * wv2.w;
  }
  gates[idx] = s;
}

__global__ __launch_bounds__(256) void lstm_ew(
    const float* __restrict__ gates, const float* __restrict__ dc,
    float* __restrict__ h_out, float* __restrict__ c_out) {
  const int idx = blockIdx.x * 256 + threadIdx.x;
  const int b = idx >> 8, d = idx & 255;
  const float ig = sigmoidf_(gates[b * 1024 + d]);
  const float fg = sigmoidf_(gates[b * 1024 + 256 + d]);
  const float gg = tanhf(gates[b * 1024 + 512 + d]);
  const float og = sigmoidf_(gates[b * 1024 + 768 + d]);
  const float c = fg * dc[idx] + ig * gg;
  c_out[idx] = c;
  h_out[idx] = og * tanhf(c);
}

__global__ __launch_bounds__(256) void hq_gemm(
    const float* __restrict__ h, const float* __restrict__ Wq, float* __restrict__ hq) {
  const int b = blockIdx.x;
  const int n = threadIdx.x;
  float s = 0.f;
  for (int k = 0; k < 256; ++k) s += h[b * 256 + k] * Wq[k * 256 + n];
  hq[b * 256 + n] = s;
}

__global__ __launch_bounds__(64) void ptr_u(
    const float* __restrict__ pref, const float* __restrict__ hq,
    const float* __restrict__ pv, float* __restrict__ u) {
  const int row = blockIdx.x;
  const int b = row / N_;
  const int lane = threadIdx.x;
  float s = 0.f;
  for (int d = lane; d < 256; d += 64)
    s += tanhf(pref[(long)row * 256 + d] + hq[b * 256 + d]) * pv[d];
  s = wave_sum64(s);
  if (lane == 0) u[row] = s;
}

__global__ __launch_bounds__(256) void policy_softmax(
    const float* __restrict__ u, const int* __restrict__ mask, float* __restrict__ pol) {
  const int b = blockIdx.x, t = threadIdx.x;
  float val = -1e30f;
  if (t < N_) val = (mask[b * N_ + t] > 0) ? u[b * N_ + t] : -1e9f;
  float m = val;
#pragma unroll
  for (int off = 32; off; off >>= 1) m = fmaxf(m, __shfl_xor(m, off));
  __shared__ float sh[8];
  const int wid = t >> 6, lane = t & 63;
  if (lane == 0) sh[wid] = m;
  __syncthreads();
  m = fmaxf(fmaxf(sh[0], sh[1]), fmaxf(sh[2], sh[3]));
  const float e = (t < N_) ? __expf(val - m) : 0.f;
  float s = e;
#pragma unroll
  for (int off = 32; off; off >>= 1) s += __shfl_xor(s, off);
  __syncthreads();
  if (lane == 0) sh[4 + wid] = s;
  __syncthreads();
  const float S = sh[4] + sh[5] + sh[6] + sh[7];
  if (t < N_) pol[b * N_ + t] = e / S;
}

extern "C" void kernel_launch(void* const* d_in, const int* in_sizes, int n_in,
                              void* d_out, int out_size, void* d_ws, size_t ws_size,
                              hipStream_t stream) {
  const float* enc_inputs = (const float*)d_in[0];
  const float* dec_input = (const float*)d_in[1];
  const float* dec_h = (const float*)d_in[2];
  const float* dec_c = (const float*)d_in[3];
  const float* gat_W = (const float*)d_in[4];
  const float* gat_att_src = (const float*)d_in[5];
  const float* gat_att_dst = (const float*)d_in[6];
  const float* gat_bias = (const float*)d_in[7];
  const float* gat_ln = (const float*)d_in[8];
  const float* enc_attn_W = (const float*)d_in[9];
  const float* enc_attn_b = (const float*)d_in[10];
  const float* enc_ln1 = (const float*)d_in[11];
  const float* enc_ffn_W1 = (const float*)d_in[12];
  const float* enc_ffn_b1 = (const float*)d_in[13];
  const float* enc_ffn_W2 = (const float*)d_in[14];
  const float* enc_ffn_b2 = (const float*)d_in[15];
  const float* enc_ln2 = (const float*)d_in[16];
  const float* lstm_Wih = (const float*)d_in[17];
  const float* lstm_Whh = (const float*)d_in[18];
  const float* lstm_b = (const float*)d_in[19];
  const float* ptr_Wref = (const float*)d_in[20];
  const float* ptr_Wq = (const float*)d_in[21];
  const float* ptr_v = (const float*)d_in[22];
  const int* adj = (const int*)d_in[23];
  const int* mask = (const int*)d_in[24];

  float* out = (float*)d_out;
  float* policy = out;                       // 12800
  float* h_out = out + 12800;                // 16384
  float* c_out = out + 12800 + 16384;        // 16384
  float* emb = out + 12800 + 16384 + 16384;  // 3,276,800

  // ---- workspace layout ----
  char* ws = (char*)d_ws;
  char* arena = ws;  // 134,217,728 B phase-overlaid
  size_t o = 134217728;
  float* xbuf = (float*)(ws + o); o += 13107200;
  float* gates = (float*)(ws + o); o += 262144;
  float* hq = (float*)(ws + o); o += 65536;
  float* ubuf = (float*)(ws + o); o += 51200;
  u16* encB = (u16*)(ws + o); o += 6553600;
  u16* xbufB = (u16*)(ws + o); o += 6553600;
  u16* embB = (u16*)(ws + o); o += 6553600;
  int* adjT = (int*)(ws + o); o += 10240000;
  unsigned* adjW = (unsigned*)(ws + o); o += 524288;
  unsigned* adjTW = (unsigned*)(ws + o); o += 524288;
  float* asrcH = (float*)(ws + o); o += 524288;
  float4* statsH = (float4*)(ws + o); o += 2097152;
  u16* gatWT = (u16*)(ws + o); o += 2097152;
  u16* WqkvT = (u16*)(ws + o); o += 1179648;
  u16* WoT = (u16*)(ws + o); o += 393216;
  u16* W1T = (u16*)(ws + o); o += 786432;
  u16* W2T = (u16*)(ws + o); o += 786432;
  u16* WrefT = (u16*)(ws + o); o += 131072;
  if (ws_size < o) fprintf(stderr, "kernel_launch: ws too small (%zu < %zu)\n", ws_size, o);
  // GAT-phase arena views
  u16* xpT = (u16*)arena;                // [B][8][256][256] bf16 (67,108,864 B)
  // encoder-phase arena views
  u16* qkvB = (u16*)arena;               // [BN][768] bf16
  u16* ctxB = (u16*)(arena + 19660800);  // [BN][256] bf16
  u16* ffnB = (u16*)(arena + 26214400);  // [BN][512] bf16
  float* pref = (float*)arena;           // pointer phase

  // ---- prep ----
  prep_weights<<<dim3(512, 21), 256, 0, stream>>>(gat_W, enc_attn_W, enc_ffn_W1, enc_ffn_W2,
                                                  ptr_Wref, gatWT, WqkvT, WoT, W1T, W2T, WrefT);
  cast_bf16<<<3200, 256, 0, stream>>>(enc_inputs, encB, 819200);
  adj_transpose<<<dim3(7, 7, 64), 256, 0, stream>>>(adj, adjT);
  adj_bits<<<64, 256, 0, stream>>>(adj, adjW);
  adj_bits2<<<64, 256, 0, stream>>>(adjT, adjTW);

  // ---- GAT stack ----
  for (int g = 0; g < G_; ++g) {
    const u16* actB = (g == 0) ? encB : xbufB;
    const float* xin = (g == 0) ? enc_inputs : xbuf;
    gat_projT<<<dim3(16, 2, 64), 256, 0, stream>>>(gatWT + (size_t)g * 524288, actB, xpT);
    gat_attvec_stats<<<512, 256, 0, stream>>>(xpT, gat_att_src + g * 2048,
                                              gat_att_dst + g * 2048, adjTW, asrcH, statsH);
    gat_msg_mfma<<<448, 256, 0, stream>>>(xpT, asrcH, statsH, adjTW, gat_bias + g * H_,
                                          xin, xbuf, xbufB);
  }
  ln_pre_kernel<<<BN_, 256, 0, stream>>>(enc_inputs, xbuf, gat_ln, emb, embB);

  // ---- Transformer encoder ----
  for (int l = 0; l < L_; ++l) {
    gemm_bf16<0, true, false, true><<<dim3(100, 6), 256, 0, stream>>>(
        embB, WqkvT + (size_t)l * 196608, enc_attn_b + l * 1024, nullptr, nullptr, qkvB,
        BN_, 768, 256);
    attn_fused<<<512, 256, 0, stream>>>(qkvB, adjW, ctxB);
    gemm_ln<256><<<200, 256, 0, stream>>>(ctxB, WoT + (size_t)l * 65536,
                                          enc_attn_b + l * 1024 + 768, emb,
                                          enc_ln1 + l * 512, emb, embB);
    gemm_bf16<1, true, false, true><<<dim3(100, 4), 256, 0, stream>>>(
        embB, W1T + (size_t)l * 131072, enc_ffn_b1 + l * 512, nullptr, nullptr, ffnB,
        BN_, 512, 256);
    gemm_ln<512><<<200, 256, 0, stream>>>(ffnB, W2T + (size_t)l * 131072,
                                          enc_ffn_b2 + l * 256, emb,
                                          enc_ln2 + l * 512, emb, embB);
  }

  // ---- LSTM + pointer ----
  lstm_gates<<<256, 256, 0, stream>>>(dec_input, dec_h, lstm_Wih, lstm_Whh, lstm_b, gates);
  lstm_ew<<<64, 256, 0, stream>>>(gates, dec_c, h_out, c_out);
  hq_gemm<<<64, 256, 0, stream>>>(h_out, ptr_Wq, hq);
  gemm_bf16<0, false, false, false><<<dim3(100, 2), 256, 0, stream>>>(
      embB, WrefT, nullptr, nullptr, pref, nullptr, BN_, 256, 256);
  ptr_u<<<BN_, 64, 0, stream>>>(pref, hq, ptr_v, ubuf);
  policy_softmax<<<B_, 256, 0, stream>>>(ubuf, mask, policy);
}